// Round 1
// baseline (195.687 us; speedup 1.0000x reference)
//
#include <hip/hip_runtime.h>
#include <hip/hip_bf16.h>

typedef float f32x4 __attribute__((ext_vector_type(4)));
typedef short bf16x8 __attribute__((ext_vector_type(8)));
typedef short short4v __attribute__((ext_vector_type(4)));

#define N_TOT 8192
#define L_OBS 20
#define P_PRED 30
#define E_DIM 64
#define H_DIM 128
#define C_DIM 2048
#define G_DIM 512
#define M_ROWS 32
#define NTH 512
#define A_PAD 200   // bf16 elems per A row: 192 + 8 pad (400B -> 2-way banks on b128 reads)

__device__ __forceinline__ unsigned short f2bf(float f) {
  union { float f; unsigned int u; } v; v.f = f;
  unsigned int u = v.u;
  return (unsigned short)((u + 0x7FFFu + ((u >> 16) & 1u)) >> 16);
}
__device__ __forceinline__ float bf2f(unsigned short b) {
  union { unsigned int u; float f; } v; v.u = ((unsigned int)b) << 16;
  return v.f;
}
__device__ __forceinline__ float sigm(float x)  { return 1.0f / (1.0f + __expf(-x)); }
__device__ __forceinline__ float tanhx(float x) { return 2.0f / (1.0f + __expf(-2.0f * x)) - 1.0f; }

__global__ __launch_bounds__(NTH, 2)
void lstm_traj(const float* __restrict__ img,      // [N][C]
               const float* __restrict__ obs_pos,  // [N][L][2]
               const float* __restrict__ obs_rel,  // [N][L][2]
               const int*   __restrict__ hist,     // [N]
               const float* __restrict__ h0,       // [H]
               const float* __restrict__ W_embed,  // [2][E]
               const float* __restrict__ b_embed,  // [E]
               const float* __restrict__ W_ih,     // [E][4H]
               const float* __restrict__ W_hh,     // [H][4H]
               const float* __restrict__ b_ih,     // [4H]
               const float* __restrict__ b_hh,     // [4H]
               const float* __restrict__ W_pred,   // [H+C][2]
               const float* __restrict__ b_pred,   // [2]
               float* __restrict__ out)            // [N][P][2]
{
  __shared__ unsigned short A_lds[2][M_ROWS][A_PAD]; // [e(64) | h(128) | pad]
  __shared__ float We_lds[2][E_DIM];
  __shared__ float be_lds[E_DIM];
  __shared__ float Wp_lds[H_DIM][2];

  const int t   = threadIdx.x;
  const int w   = t >> 6;        // wave 0..7
  const int l   = t & 63;        // lane
  const int u15 = l & 15;        // MFMA: D col / A row index
  const int rq  = l >> 4;        // MFMA: k-group / D row-quad
  const int u   = w * 16 + u15;  // owned hidden unit 0..127
  const int wg0 = blockIdx.x * M_ROWS;
  const int grow = t >> 4;       // 0..31 : row for e/rel/img work
  const int gj   = t & 15;       // 0..15 : slot within row group

  // ---- stage small weights to LDS ----
  if (t < 128) We_lds[t >> 6][t & 63] = W_embed[t];
  if (t < 64)  be_lds[t] = b_embed[t];
  if (t >= 128 && t < 384) ((float*)Wp_lds)[t - 128] = W_pred[t - 128];
  __syncthreads();

  // ---- B fragments (weights) into registers: 24 frags = 96 VGPR ----
  bf16x8 B[4][6];
#pragma unroll
  for (int ks = 0; ks < 6; ++ks) {
#pragma unroll
    for (int i = 0; i < 8; ++i) {
      const int k = ks * 32 + rq * 8 + i;
      const float* Wrow = (k < E_DIM) ? (W_ih + k * G_DIM) : (W_hh + (k - E_DIM) * G_DIM);
#pragma unroll
      for (int gt = 0; gt < 4; ++gt)
        B[gt][ks][i] = (short)f2bf(Wrow[gt * 128 + u]);
    }
  }

  float bias[4];
#pragma unroll
  for (int gt = 0; gt < 4; ++gt) bias[gt] = b_ih[gt * 128 + u] + b_hh[gt * 128 + u];

  // ---- per-lane recurrent state: rows rt*16 + rq*4 + q, unit u ----
  const float h0u = h0[u];
  const unsigned short h0b = f2bf(h0u);
  unsigned short hb[2][4];
  float cs[2][4];
  int   hv_[2][4];
#pragma unroll
  for (int rt = 0; rt < 2; ++rt)
#pragma unroll
    for (int q = 0; q < 4; ++q) {
      const int row = rt * 16 + rq * 4 + q;
      hb[rt][q] = h0b; cs[rt][q] = h0u;
      hv_[rt][q] = hist[wg0 + row];
      A_lds[0][row][64 + u] = h0b;
    }

  // ---- e for obs step 0 (uses obs_rel[:,1,:]) ----
  {
    const float* rp = obs_rel + (wg0 + grow) * (L_OBS * 2) + 2;
    const float r0 = rp[0], r1 = rp[1];
    short4v ep;
#pragma unroll
    for (int i = 0; i < 4; ++i) {
      const int j = gj * 4 + i;
      float e = fmaf(r0, We_lds[0][j], fmaf(r1, We_lds[1][j], be_lds[j]));
      ep[i] = (short)f2bf(fmaxf(e, 0.0f));
    }
    *(short4v*)&A_lds[0][grow][gj * 4] = ep;
  }

  // ---- pos init + img_proj (16 lanes per row, coalesced float4) ----
  float pos0 = obs_pos[(wg0 + grow) * (L_OBS * 2) + 2 * (L_OBS - 1)];
  float pos1 = obs_pos[(wg0 + grow) * (L_OBS * 2) + 2 * (L_OBS - 1) + 1];
  float ip0 = 0.0f, ip1 = 0.0f;
  {
    const float* irow = img + (long)(wg0 + grow) * C_DIM;
#pragma unroll 4
    for (int i = 0; i < 32; ++i) {
      const int k0 = i * 64 + gj * 4;
      f32x4 v  = *(const f32x4*)(irow + k0);
      f32x4 wa = *(const f32x4*)(W_pred + (H_DIM + k0) * 2);
      f32x4 wb = *(const f32x4*)(W_pred + (H_DIM + k0) * 2 + 4);
      ip0 += v.x * wa.x + v.y * wa.z + v.z * wb.x + v.w * wb.z;
      ip1 += v.x * wa.y + v.y * wa.w + v.z * wb.y + v.w * wb.w;
    }
#pragma unroll
    for (int m = 8; m >= 1; m >>= 1) {
      ip0 += __shfl_xor(ip0, m, 64);
      ip1 += __shfl_xor(ip1, m, 64);
    }
    ip0 += b_pred[0]; ip1 += b_pred[1];
  }
  __syncthreads();

  int cur = 0;

  auto mfma_step = [&](int cur_, int nxt_, bool do_mask, int thr) {
    f32x4 acc[2][4];
#pragma unroll
    for (int rt = 0; rt < 2; ++rt) {
#pragma unroll
      for (int gt = 0; gt < 4; ++gt) { acc[rt][gt].x = 0.f; acc[rt][gt].y = 0.f; acc[rt][gt].z = 0.f; acc[rt][gt].w = 0.f; }
#pragma unroll
      for (int ks = 0; ks < 6; ++ks) {
        bf16x8 a = *(const bf16x8*)&A_lds[cur_][rt * 16 + u15][ks * 32 + rq * 8];
#pragma unroll
        for (int gt = 0; gt < 4; ++gt)
          acc[rt][gt] = __builtin_amdgcn_mfma_f32_16x16x32_bf16(a, B[gt][ks], acc[rt][gt], 0, 0, 0);
      }
    }
#pragma unroll
    for (int rt = 0; rt < 2; ++rt)
#pragma unroll
      for (int q = 0; q < 4; ++q) {
        const float gi = acc[rt][0][q] + bias[0];
        const float gf = acc[rt][1][q] + bias[1];
        const float gg = acc[rt][2][q] + bias[2];
        const float go = acc[rt][3][q] + bias[3];
        const float cn = sigm(gf) * cs[rt][q] + sigm(gi) * tanhx(gg);
        const float hn = sigm(go) * tanhx(cn);
        const bool m = (!do_mask) || (hv_[rt][q] > thr);
        if (m) { cs[rt][q] = cn; hb[rt][q] = f2bf(hn); }
        A_lds[nxt_][rt * 16 + rq * 4 + q][64 + u] = hb[rt][q];
      }
  };

  // ================= obs phase: 19 masked steps =================
#pragma unroll 1
  for (int s = 0; s < L_OBS - 1; ++s) {
    const int nxt = cur ^ 1;
    mfma_step(cur, nxt, true, (L_OBS - 1) - s);
    if (s < L_OBS - 2) {  // prefetch e_{s+1} from obs_rel[:, s+2, :]
      const float* rp = obs_rel + (wg0 + grow) * (L_OBS * 2) + (s + 2) * 2;
      const float r0 = rp[0], r1 = rp[1];
      short4v ep;
#pragma unroll
      for (int i = 0; i < 4; ++i) {
        const int j = gj * 4 + i;
        float e = fmaf(r0, We_lds[0][j], fmaf(r1, We_lds[1][j], be_lds[j]));
        ep[i] = (short)f2bf(fmaxf(e, 0.0f));
      }
      *(short4v*)&A_lds[nxt][grow][gj * 4] = ep;
    }
    cur = nxt;
    __syncthreads();
  }

  // ================= pred phase: 30 steps =================
#pragma unroll 1
  for (int p = 0; p < P_PRED; ++p) {
    // rel = h @ Wp_h + img_proj   (16-lane group reduction per row)
    bf16x8 hvv = *(const bf16x8*)&A_lds[cur][grow][64 + gj * 8];
    float s0 = 0.0f, s1 = 0.0f;
#pragma unroll
    for (int i = 0; i < 8; ++i) {
      const float hf = bf2f((unsigned short)hvv[i]);
      s0 = fmaf(hf, Wp_lds[gj * 8 + i][0], s0);
      s1 = fmaf(hf, Wp_lds[gj * 8 + i][1], s1);
    }
#pragma unroll
    for (int m = 8; m >= 1; m >>= 1) {
      s0 += __shfl_xor(s0, m, 64);
      s1 += __shfl_xor(s1, m, 64);
    }
    const float rel0 = s0 + ip0, rel1 = s1 + ip1;
    pos0 += rel0; pos1 += rel1;
    if (gj == 0) {
      float2 o; o.x = pos0; o.y = pos1;
      *(float2*)&out[((long)(wg0 + grow) * P_PRED + p) * 2] = o;
    }
    if (p == P_PRED - 1) break;

    // e = relu(rel @ W_embed + b_embed) into current buffer
    short4v ep;
#pragma unroll
    for (int i = 0; i < 4; ++i) {
      const int j = gj * 4 + i;
      float e = fmaf(rel0, We_lds[0][j], fmaf(rel1, We_lds[1][j], be_lds[j]));
      ep[i] = (short)f2bf(fmaxf(e, 0.0f));
    }
    *(short4v*)&A_lds[cur][grow][gj * 4] = ep;
    __syncthreads();

    const int nxt = cur ^ 1;
    mfma_step(cur, nxt, false, 0);
    cur = nxt;
    __syncthreads();
  }
}

extern "C" void kernel_launch(void* const* d_in, const int* in_sizes, int n_in,
                              void* d_out, int out_size, void* d_ws, size_t ws_size,
                              hipStream_t stream) {
  (void)in_sizes; (void)n_in; (void)out_size; (void)d_ws; (void)ws_size;
  lstm_traj<<<dim3(N_TOT / M_ROWS), dim3(NTH), 0, stream>>>(
      (const float*)d_in[0],  // img_embedding
      (const float*)d_in[1],  // obs_pos
      (const float*)d_in[2],  // obs_pos_rel
      (const int*)  d_in[3],  // obs_hist_size
      (const float*)d_in[4],  // h0
      (const float*)d_in[5],  // W_embed
      (const float*)d_in[6],  // b_embed
      (const float*)d_in[7],  // W_ih
      (const float*)d_in[8],  // W_hh
      (const float*)d_in[9],  // b_ih
      (const float*)d_in[10], // b_hh
      (const float*)d_in[11], // W_pred
      (const float*)d_in[12], // b_pred
      (float*)d_out);
}